// Round 13
// baseline (1232.987 us; speedup 1.0000x reference)
//
#include <hip/hip_runtime.h>
#include <stdint.h>

// ---------------------------------------------------------------------------
// Fused LSTM cell, round 13 = round 11 with 2-deep/48KB LDS (3 blocks/CU).
//  prep_all: xb[131072][128] bf16 (pad, k127=1.0), hb[131072][256] bf16,
//            Bt fragment blob (bias @ k127). Unchanged.
//  lstm_main: 512 thr (8 waves = 2 wr x 4 wcq), tile 128 rows x 256 gatecols,
//    12 stages BK=32, 3 gl_lds/wave/stage (1 A + 2 B, homogeneous FIFO),
//    8 ds_read_b128 + 16 MFMA per wave-stage. 2-deep LDS dbuf (48 KiB) ->
//    3 blocks/CU = 24 waves (launch_bounds(512,6), VGPR<=84). Step:
//    VMW(3); bar; COMPUTE(S); bar; STAGE(S+2)  -- overwrite-safe, loads
//    never drained. C-prefetch at S==8; FIFO-exact VMW 19/19/0 tail.
// ---------------------------------------------------------------------------

typedef short bf16x8 __attribute__((ext_vector_type(8)));
typedef float f32x4  __attribute__((ext_vector_type(4)));

#define HDIM   256
#define INDIM  100
#define NROWS  131072
// d_ws layout (ushort offsets): Bt @0 (768 KiB), xb @1 MiB, hb @34 MiB
#define BT_OFF 0
#define XB_OFF (1048576 / 2)
#define HB_OFF (35651584 / 2)
#define ABUF(b) ((b) * 8192)
#define BBUF(b) (16384 + (b) * 16384)

__device__ __forceinline__ float fexp(float x) {
  return __builtin_amdgcn_exp2f(x * 1.44269504088896340736f);
}
__device__ __forceinline__ float frcp(float x) { return __builtin_amdgcn_rcpf(x); }
__device__ __forceinline__ float sigm(float x) { return frcp(1.0f + fexp(-x)); }
__device__ __forceinline__ float tanh_fast(float x) {
  return 1.0f - 2.0f * frcp(1.0f + fexp(2.0f * x));
}
__device__ __forceinline__ unsigned short f2bf_rne(float f) {
  union { float f; uint32_t u; } v; v.f = f;
  return (unsigned short)((v.u + 0x7FFFu + ((v.u >> 16) & 1u)) >> 16);
}
__device__ __forceinline__ void gl16(const void* g, void* l) {
  __builtin_amdgcn_global_load_lds(
      (const __attribute__((address_space(1))) unsigned int*)g,
      (__attribute__((address_space(3))) unsigned int*)l, 16, 0, 0);
}
#define VMW(N) asm volatile("s_waitcnt vmcnt(" #N ")" ::: "memory")

// ---- prep: 3 jobs (unchanged) ---------------------------------------------
__global__ void prep_all(const float* __restrict__ X, const float* __restrict__ Hin,
                         const float* __restrict__ Wx, const float* __restrict__ Wh,
                         const float* __restrict__ bxp, const float* __restrict__ bhp,
                         unsigned short* __restrict__ ws) {
  const int b = blockIdx.x, tid = threadIdx.x;
  if (b < 8192) {                        // ---- x -> xb[131072][128] ----
    const int t   = b * 256 + tid;
    const int row = t >> 4, k0 = (t & 15) * 8;
    const float* xp = X + (size_t)row * INDIM;
    float4 lo = make_float4(0.f, 0.f, 0.f, 0.f);
    float4 hi = make_float4(0.f, 0.f, 0.f, 0.f);
    if (k0 + 4 <= INDIM) lo = *reinterpret_cast<const float4*>(xp + k0);
    if (k0 + 8 <= INDIM) hi = *reinterpret_cast<const float4*>(xp + k0 + 4);
    float va[8] = {lo.x, lo.y, lo.z, lo.w, hi.x, hi.y, hi.z, hi.w};
    unsigned short o[8];
#pragma unroll
    for (int e = 0; e < 8; ++e) {
      const int k = k0 + e;
      const float f = (k < INDIM) ? va[e] : (k == 127 ? 1.0f : 0.0f);
      o[e] = f2bf_rne(f);
    }
    *reinterpret_cast<bf16x8*>(ws + XB_OFF + (size_t)row * 128 + k0) =
        *reinterpret_cast<bf16x8*>(o);
  } else if (b < 24576) {                // ---- h -> hb[131072][256] ----
    const int t   = (b - 8192) * 256 + tid;
    const int row = t >> 5, k0 = (t & 31) * 8;
    const float* hp = Hin + (size_t)row * HDIM + k0;
    const float4 lo = *reinterpret_cast<const float4*>(hp);
    const float4 hi = *reinterpret_cast<const float4*>(hp + 4);
    unsigned short o[8] = {f2bf_rne(lo.x), f2bf_rne(lo.y), f2bf_rne(lo.z),
                           f2bf_rne(lo.w), f2bf_rne(hi.x), f2bf_rne(hi.y),
                           f2bf_rne(hi.z), f2bf_rne(hi.w)};
    *reinterpret_cast<bf16x8*>(ws + HB_OFF + (size_t)row * 256 + k0) =
        *reinterpret_cast<bf16x8*>(o);
  } else {                               // ---- W -> Bt blob (bias @ k127) --
    const int unit = (b - 24576) * 4 + (tid >> 6);   // 0..767
    const int lane = tid & 63;
    const int kst  = unit % 12;
    const int fidb = unit / 12;
    const int bn   = fidb >> 3, fid = fidb & 7;
    const int g    = fid >> 1,  wc  = fid & 1;
    const int wcol = g * HDIM + bn * 32 + wc * 16 + (lane & 15);
    const int kb   = kst * 32 + (lane >> 4) * 8;
    unsigned short v[8];
#pragma unroll
    for (int e = 0; e < 8; ++e) {
      const int k = kb + e;              // 0..383
      float f = 0.0f;
      if (k < INDIM)     f = Wx[(size_t)k * 1024 + wcol];
      else if (k == 127) f = bxp[wcol] + bhp[wcol];
      else if (k >= 128) f = Wh[(size_t)(k - 128) * 1024 + wcol];
      v[e] = f2bf_rne(f);
    }
    *reinterpret_cast<bf16x8*>(ws + BT_OFF + (size_t)unit * 512 + lane * 8) =
        *reinterpret_cast<bf16x8*>(v);
  }
}

// ---- main -----------------------------------------------------------------
__global__ __launch_bounds__(512, 6)
void lstm_main(const unsigned short* __restrict__ ws,
               const float* __restrict__ Cin, float* __restrict__ out)
{
  __shared__ unsigned char smem[49152];  // 2 x (8K A + 16K B)

  const int tid  = threadIdx.x;
  const int orig = blockIdx.x;           // 0..4095 (%8==0 -> bijective)
  const int lg   = ((orig & 7) << 9) | (orig >> 3);
  const int mt   = lg >> 2;              // M tile 0..1023 (128 rows)
  const int bnn  = lg & 3;               // N tile 0..3 (64 H-cols)

  const int lane = tid & 63;
  const int l15  = lane & 15;
  const int kq   = lane >> 4;
  const int wid  = tid >> 6;             // 0..7
  const int wr   = wid >> 2;             // 0..1: 64-row group
  const int wcq  = wid & 3;              // 0..3: 16-hcol quarter
  const int ch   = bnn * 64 + wcq * 16 + l15;
  const int sx   = (l15 >> 1) & 3;       // read-side XOR (== (row>>1)&3)

  const unsigned short* xb = ws + XB_OFF;
  const unsigned short* hb = ws + HB_OFF;
  const unsigned short* Bt = ws + BT_OFF;

  // A staging: 1 gl_lds/wave/stage
  const int ci = wid * 64 + lane;                // 0..511
  const int r  = ci >> 2;                        // tile row 0..127
  const int sc = (ci & 3) ^ ((r >> 1) & 3);      // pre-swizzled chunk
  const unsigned short* xsrc = xb + (size_t)(mt * 128 + r) * 128 + sc * 8;
  const unsigned short* hsrc = hb + (size_t)(mt * 128 + r) * 256 + sc * 8;

  // B staging: 2 gl_lds/wave/stage (units wid*2, wid*2+1 of 16)
  const unsigned short* bsrc[2];
#pragma unroll
  for (int j = 0; j < 2; ++j) {
    const int u  = wid * 2 + j;                  // local unit 0..15
    const int gu = (bnn * 2 + (u >> 3)) * 8 + (u & 7);
    bsrc[j] = Bt + (size_t)gu * 12 * 512 + lane * 8;
  }
  const int adst = wid * 1024;           // wave-uniform LDS sub-offsets
  const int bd0  = (wid * 2 + 0) * 1024;
  const int bd1  = (wid * 2 + 1) * 1024;

  f32x4 acc[4][4];
#pragma unroll
  for (int m = 0; m < 4; ++m)
#pragma unroll
    for (int g = 0; g < 4; ++g)
#pragma unroll
      for (int e = 0; e < 4; ++e) acc[m][g][e] = 0.0f;

  float cvv[4][4];

  auto STAGE = [&](int T) {
    char* Ad = (char*)smem + ABUF(T & 1);
    char* Bd = (char*)smem + BBUF(T & 1);
    if (T < 4) gl16(xsrc + T * 32, Ad + adst);
    else       gl16(hsrc + (T - 4) * 32, Ad + adst);
    gl16(bsrc[0] + T * 512, Bd + bd0);
    gl16(bsrc[1] + T * 512, Bd + bd1);
  };

  auto COMPUTE = [&](int S) {
    const unsigned short* Ab = (const unsigned short*)(smem + ABUF(S & 1));
    const unsigned short* Bb = (const unsigned short*)(smem + BBUF(S & 1));
    bf16x8 afr[4], bfr[4];
#pragma unroll
    for (int m = 0; m < 4; ++m)
      afr[m] = *reinterpret_cast<const bf16x8*>(
          Ab + (wr * 64 + m * 16 + l15) * 32 + ((kq ^ sx) * 8));
#pragma unroll
    for (int g = 0; g < 4; ++g) {
      const int ub = (wcq >> 1) * 8 + g * 2 + (wcq & 1);
      bfr[g] = *reinterpret_cast<const bf16x8*>(Bb + ub * 512 + lane * 8);
    }
    __builtin_amdgcn_s_setprio(1);
#pragma unroll
    for (int m = 0; m < 4; ++m)
#pragma unroll
      for (int g = 0; g < 4; ++g)
        acc[m][g] = __builtin_amdgcn_mfma_f32_16x16x32_bf16(
            afr[m], bfr[g], acc[m][g], 0, 0, 0);
    __builtin_amdgcn_s_setprio(0);
  };

  // prologue: 2 stages (6 gl_lds) in flight
  STAGE(0);
  STAGE(1);

  // FIFO (3 gl_lds/stage/wave): at step S, VMW(N) with N = ops newer than
  // stage S. Steady: stage S+1 only -> VMW(3). C-prefetch (16 loads) issued
  // at end of S==8 (after STAGE(10)): S=9 -> S(10)3+C16 = VMW(19);
  // S=10 -> C16+S(11)3 = VMW(19); S=11 -> VMW(0) (drains C too).
  // Two barriers/step: compute(S) fully done before any wave's STAGE(S+2)
  // overwrites buffer S&1.
#define STEP(S, KN)                                               \
  do {                                                            \
    VMW(KN);                                                      \
    __builtin_amdgcn_s_barrier();                                 \
    COMPUTE(S);                                                   \
    __builtin_amdgcn_s_barrier();                                 \
    if ((S) + 2 < 12) STAGE((S) + 2);                             \
    if ((S) == 8) {                                               \
      const float* cb =                                           \
          Cin + ((size_t)mt * 128 + wr * 64 + kq * 4) * HDIM + ch;\
      _Pragma("unroll")                                           \
      for (int m = 0; m < 4; ++m)                                 \
        _Pragma("unroll")                                         \
        for (int e = 0; e < 4; ++e)                               \
          cvv[m][e] = __builtin_nontemporal_load(                 \
              cb + (size_t)(m * 16 + e) * HDIM);                  \
    }                                                             \
  } while (0)

  STEP(0, 3);  STEP(1, 3);  STEP(2, 3);  STEP(3, 3);
  STEP(4, 3);  STEP(5, 3);  STEP(6, 3);  STEP(7, 3);
  STEP(8, 3);  STEP(9, 19); STEP(10, 19); STEP(11, 0);
#undef STEP

  // ---- epilogue: bias folded in acc; lane-local gate combine -------------
  // (waves are phase-locked by step 11's trailing barrier -> each 128B
  //  output line's wcq-sibling halves coalesce in L2)
  float* op  = out + ((size_t)mt * 128 + wr * 64 + kq * 4) * HDIM + ch;
  float* op2 = op + (size_t)NROWS * HDIM;
#pragma unroll
  for (int m = 0; m < 4; ++m) {
#pragma unroll
    for (int e = 0; e < 4; ++e) {
      const float pi = acc[m][0][e];
      const float pf = acc[m][1][e];
      const float pg = acc[m][2][e];
      const float po = acc[m][3][e];
      const float ig = sigm(pi), fg = sigm(pf);
      const float gg = tanh_fast(pg), og = sigm(po);
      const float co = fg * cvv[m][e] + ig * gg;
      const float ho = og * tanh_fast(co);
      __builtin_nontemporal_store(co, op  + (size_t)(m * 16 + e) * HDIM);
      __builtin_nontemporal_store(ho, op2 + (size_t)(m * 16 + e) * HDIM);
    }
  }
}

extern "C" void kernel_launch(void* const* d_in, const int* in_sizes, int n_in,
                              void* d_out, int out_size, void* d_ws, size_t ws_size,
                              hipStream_t stream) {
  const float* x  = (const float*)d_in[0];
  const float* C  = (const float*)d_in[1];
  const float* h  = (const float*)d_in[2];
  const float* Wx = (const float*)d_in[3];
  const float* Wh = (const float*)d_in[4];
  const float* bx = (const float*)d_in[5];
  const float* bh = (const float*)d_in[6];
  float* o = (float*)d_out;
  unsigned short* ws = (unsigned short*)d_ws;   // ~98 MiB used

  prep_all<<<dim3(24768), dim3(256), 0, stream>>>(x, h, Wx, Wh, bx, bh, ws);
  lstm_main<<<dim3(4096), dim3(512), 0, stream>>>(ws, C, o);
}

// Round 15
// 208.341 us; speedup vs baseline: 5.9181x; 5.9181x over previous
//
#include <hip/hip_runtime.h>
#include <stdint.h>

// ---------------------------------------------------------------------------
// Fused LSTM cell, round 15 = round 14 with the NT-store type fixed
// (ext_vector f32x4 instead of HIP float4; builtin requires scalar/ext-vector).
//  prep_all: xb[131072][128] bf16 (pad, k127=1.0 bias driver),
//            hb[131072][256] bf16, Bt fragment blob (bias @ k127). Unchanged.
//  lstm_main: 512 thr (8 waves = 2 wr x 4 wcq), tile 128 x 256 gatecols,
//    12 stages BK=32, 3 gl_lds/wave/stage homogeneous FIFO, 3-deep LDS
//    multibuffer, counted VMW(3)/19/16 schedule -- byte-identical to r11.
//  Epilogue: 4 m-passes; gate-combine -> LDS transpose [32][68] f32
//    (2-way aliasing only) -> f32x4 reads -> NT global_store_dwordx4,
//    full 128B lines per wave. Store issues 32->8 per thread.
// ---------------------------------------------------------------------------

typedef short bf16x8 __attribute__((ext_vector_type(8)));
typedef float f32x4  __attribute__((ext_vector_type(4)));

#define HDIM   256
#define INDIM  100
#define NROWS  131072
// d_ws layout (ushort offsets): Bt @0 (768 KiB), xb @1 MiB, hb @34 MiB
#define BT_OFF 0
#define XB_OFF (1048576 / 2)
#define HB_OFF (35651584 / 2)
#define ABUF(b) ((b) * 8192)
#define BBUF(b) (24576 + (b) * 16384)

__device__ __forceinline__ float fexp(float x) {
  return __builtin_amdgcn_exp2f(x * 1.44269504088896340736f);
}
__device__ __forceinline__ float frcp(float x) { return __builtin_amdgcn_rcpf(x); }
__device__ __forceinline__ float sigm(float x) { return frcp(1.0f + fexp(-x)); }
__device__ __forceinline__ float tanh_fast(float x) {
  return 1.0f - 2.0f * frcp(1.0f + fexp(2.0f * x));
}
__device__ __forceinline__ unsigned short f2bf_rne(float f) {
  union { float f; uint32_t u; } v; v.f = f;
  return (unsigned short)((v.u + 0x7FFFu + ((v.u >> 16) & 1u)) >> 16);
}
__device__ __forceinline__ void gl16(const void* g, void* l) {
  __builtin_amdgcn_global_load_lds(
      (const __attribute__((address_space(1))) unsigned int*)g,
      (__attribute__((address_space(3))) unsigned int*)l, 16, 0, 0);
}
#define VMW(N) asm volatile("s_waitcnt vmcnt(" #N ")" ::: "memory")
// barrier with LDS-drain only (no vmcnt drain -> NT stores stay in flight)
#define LBAR() asm volatile("s_waitcnt lgkmcnt(0)\n\ts_barrier" ::: "memory")

// ---- prep: 3 jobs (unchanged) ---------------------------------------------
__global__ void prep_all(const float* __restrict__ X, const float* __restrict__ Hin,
                         const float* __restrict__ Wx, const float* __restrict__ Wh,
                         const float* __restrict__ bxp, const float* __restrict__ bhp,
                         unsigned short* __restrict__ ws) {
  const int b = blockIdx.x, tid = threadIdx.x;
  if (b < 8192) {                        // ---- x -> xb[131072][128] ----
    const int t   = b * 256 + tid;
    const int row = t >> 4, k0 = (t & 15) * 8;
    const float* xp = X + (size_t)row * INDIM;
    float4 lo = make_float4(0.f, 0.f, 0.f, 0.f);
    float4 hi = make_float4(0.f, 0.f, 0.f, 0.f);
    if (k0 + 4 <= INDIM) lo = *reinterpret_cast<const float4*>(xp + k0);
    if (k0 + 8 <= INDIM) hi = *reinterpret_cast<const float4*>(xp + k0 + 4);
    float va[8] = {lo.x, lo.y, lo.z, lo.w, hi.x, hi.y, hi.z, hi.w};
    unsigned short o[8];
#pragma unroll
    for (int e = 0; e < 8; ++e) {
      const int k = k0 + e;
      const float f = (k < INDIM) ? va[e] : (k == 127 ? 1.0f : 0.0f);
      o[e] = f2bf_rne(f);
    }
    *reinterpret_cast<bf16x8*>(ws + XB_OFF + (size_t)row * 128 + k0) =
        *reinterpret_cast<bf16x8*>(o);
  } else if (b < 24576) {                // ---- h -> hb[131072][256] ----
    const int t   = (b - 8192) * 256 + tid;
    const int row = t >> 5, k0 = (t & 31) * 8;
    const float* hp = Hin + (size_t)row * HDIM + k0;
    const float4 lo = *reinterpret_cast<const float4*>(hp);
    const float4 hi = *reinterpret_cast<const float4*>(hp + 4);
    unsigned short o[8] = {f2bf_rne(lo.x), f2bf_rne(lo.y), f2bf_rne(lo.z),
                           f2bf_rne(lo.w), f2bf_rne(hi.x), f2bf_rne(hi.y),
                           f2bf_rne(hi.z), f2bf_rne(hi.w)};
    *reinterpret_cast<bf16x8*>(ws + HB_OFF + (size_t)row * 256 + k0) =
        *reinterpret_cast<bf16x8*>(o);
  } else {                               // ---- W -> Bt blob (bias @ k127) --
    const int unit = (b - 24576) * 4 + (tid >> 6);   // 0..767
    const int lane = tid & 63;
    const int kst  = unit % 12;
    const int fidb = unit / 12;
    const int bn   = fidb >> 3, fid = fidb & 7;
    const int g    = fid >> 1,  wc  = fid & 1;
    const int wcol = g * HDIM + bn * 32 + wc * 16 + (lane & 15);
    const int kb   = kst * 32 + (lane >> 4) * 8;
    unsigned short v[8];
#pragma unroll
    for (int e = 0; e < 8; ++e) {
      const int k = kb + e;              // 0..383
      float f = 0.0f;
      if (k < INDIM)     f = Wx[(size_t)k * 1024 + wcol];
      else if (k == 127) f = bxp[wcol] + bhp[wcol];
      else if (k >= 128) f = Wh[(size_t)(k - 128) * 1024 + wcol];
      v[e] = f2bf_rne(f);
    }
    *reinterpret_cast<bf16x8*>(ws + BT_OFF + (size_t)unit * 512 + lane * 8) =
        *reinterpret_cast<bf16x8*>(v);
  }
}

// ---- main -----------------------------------------------------------------
__global__ __launch_bounds__(512, 2)
void lstm_main(const unsigned short* __restrict__ ws,
               const float* __restrict__ Cin, float* __restrict__ out)
{
  __shared__ unsigned char smem[73728];  // 3 x (8K A + 16K B)

  const int tid  = threadIdx.x;
  const int orig = blockIdx.x;           // 0..4095 (%8==0 -> bijective)
  const int lg   = ((orig & 7) << 9) | (orig >> 3);
  const int mt   = lg >> 2;              // M tile 0..1023 (128 rows)
  const int bnn  = lg & 3;               // N tile 0..3 (64 H-cols)

  const int lane = tid & 63;
  const int l15  = lane & 15;
  const int kq   = lane >> 4;
  const int wid  = tid >> 6;             // 0..7
  const int wr   = wid >> 2;             // 0..1: 64-row group
  const int wcq  = wid & 3;              // 0..3: 16-hcol quarter
  const int ch   = bnn * 64 + wcq * 16 + l15;
  const int sx   = (l15 >> 1) & 3;       // read-side XOR (== (row>>1)&3)

  const unsigned short* xb = ws + XB_OFF;
  const unsigned short* hb = ws + HB_OFF;
  const unsigned short* Bt = ws + BT_OFF;

  // A staging: 1 gl_lds/wave/stage
  const int ci = wid * 64 + lane;                // 0..511
  const int r  = ci >> 2;                        // tile row 0..127
  const int sc = (ci & 3) ^ ((r >> 1) & 3);      // pre-swizzled chunk
  const unsigned short* xsrc = xb + (size_t)(mt * 128 + r) * 128 + sc * 8;
  const unsigned short* hsrc = hb + (size_t)(mt * 128 + r) * 256 + sc * 8;

  // B staging: 2 gl_lds/wave/stage (units wid*2, wid*2+1 of 16)
  const unsigned short* bsrc[2];
#pragma unroll
  for (int j = 0; j < 2; ++j) {
    const int u  = wid * 2 + j;                  // local unit 0..15
    const int gu = (bnn * 2 + (u >> 3)) * 8 + (u & 7);
    bsrc[j] = Bt + (size_t)gu * 12 * 512 + lane * 8;
  }
  const int adst = wid * 1024;           // wave-uniform LDS sub-offsets
  const int bd0  = (wid * 2 + 0) * 1024;
  const int bd1  = (wid * 2 + 1) * 1024;

  f32x4 acc[4][4];
#pragma unroll
  for (int m = 0; m < 4; ++m)
#pragma unroll
    for (int g = 0; g < 4; ++g)
#pragma unroll
      for (int e = 0; e < 4; ++e) acc[m][g][e] = 0.0f;

  float cvv[4][4];

  auto STAGE = [&](int T) {
    char* Ad = (char*)smem + ABUF(T % 3);
    char* Bd = (char*)smem + BBUF(T % 3);
    if (T < 4) gl16(xsrc + T * 32, Ad + adst);
    else       gl16(hsrc + (T - 4) * 32, Ad + adst);
    gl16(bsrc[0] + T * 512, Bd + bd0);
    gl16(bsrc[1] + T * 512, Bd + bd1);
  };

  auto COMPUTE = [&](int S) {
    const unsigned short* Ab = (const unsigned short*)(smem + ABUF(S % 3));
    const unsigned short* Bb = (const unsigned short*)(smem + BBUF(S % 3));
    bf16x8 afr[4], bfr[4];
#pragma unroll
    for (int m = 0; m < 4; ++m)
      afr[m] = *reinterpret_cast<const bf16x8*>(
          Ab + (wr * 64 + m * 16 + l15) * 32 + ((kq ^ sx) * 8));
#pragma unroll
    for (int g = 0; g < 4; ++g) {
      const int ub = (wcq >> 1) * 8 + g * 2 + (wcq & 1);
      bfr[g] = *reinterpret_cast<const bf16x8*>(Bb + ub * 512 + lane * 8);
    }
    __builtin_amdgcn_s_setprio(1);
#pragma unroll
    for (int m = 0; m < 4; ++m)
#pragma unroll
      for (int g = 0; g < 4; ++g)
        acc[m][g] = __builtin_amdgcn_mfma_f32_16x16x32_bf16(
            afr[m], bfr[g], acc[m][g], 0, 0, 0);
    __builtin_amdgcn_s_setprio(0);
  };

  // prologue: 2 stages (6 gl_lds) in flight
  STAGE(0);
  STAGE(1);

  // FIFO (3 gl_lds/stage/wave): steady VMW(3). C prefetch (16 loads) issued
  // at S==9 after STAGE(11): S=10 -> 3+16=VMW(19); S=11 -> VMW(16).
#define STEP(S, KN)                                               \
  do {                                                            \
    VMW(KN);                                                      \
    __builtin_amdgcn_s_barrier();                                 \
    if ((S) + 2 < 12) STAGE((S) + 2);                             \
    if ((S) == 9) {                                               \
      const float* cb =                                           \
          Cin + ((size_t)mt * 128 + wr * 64 + kq * 4) * HDIM + ch;\
      _Pragma("unroll")                                           \
      for (int m = 0; m < 4; ++m)                                 \
        _Pragma("unroll")                                         \
        for (int e = 0; e < 4; ++e)                               \
          cvv[m][e] = __builtin_nontemporal_load(                 \
              cb + (size_t)(m * 16 + e) * HDIM);                  \
    }                                                             \
    COMPUTE(S);                                                   \
  } while (0)

  STEP(0, 3);  STEP(1, 3);  STEP(2, 3);  STEP(3, 3);
  STEP(4, 3);  STEP(5, 3);  STEP(6, 3);  STEP(7, 3);
  STEP(8, 3);  STEP(9, 3);  STEP(10, 19); STEP(11, 16);
#undef STEP

  VMW(0);                                // C prefetch landed

  // ---- coalesced epilogue: 4 m-passes through an LDS transpose ----------
  // Free LDS after the K-loop (last stage S=11 used ABUF(2)/BBUF(2)):
  //   c-buf @0 (A bufs 0/1), h-buf @24576 (B bufs 0/1); [32][68] f32 each
  //   (8704 B used). 2-way bank aliasing only. All waves passed STEP(11)'s
  //   barrier, so bufs 0/1 are dead before the first pass write.
  float* tc = (float*)(smem);
  float* th = (float*)(smem + 24576);
  const int rl = tid >> 4;               // read row 0..31
  const int c4 = (tid & 15) * 4;         // read col (f32x4)
  const size_t rg = (size_t)mt * 128 + (tid >> 8) * 64 + ((tid >> 4) & 15);
  float* opc = out + rg * HDIM + bnn * 64 + c4;
  float* oph = opc + (size_t)NROWS * HDIM;

#pragma unroll
  for (int m = 0; m < 4; ++m) {
#pragma unroll
    for (int e = 0; e < 4; ++e) {
      const float pi = acc[m][0][e];
      const float pf = acc[m][1][e];
      const float pg = acc[m][2][e];
      const float po = acc[m][3][e];
      const float ig = sigm(pi), fg = sigm(pf);
      const float gg = tanh_fast(pg), og = sigm(po);
      const float co = fg * cvv[m][e] + ig * gg;
      const float ho = og * tanh_fast(co);
      const int rloc = wr * 16 + kq * 4 + e;       // 0..31
      const int cloc = wcq * 16 + l15;             // 0..63
      tc[rloc * 68 + cloc] = co;
      th[rloc * 68 + cloc] = ho;
    }
    LBAR();                              // writes visible to all waves
    {
      const f32x4 vc = *reinterpret_cast<const f32x4*>(tc + rl * 68 + c4);
      const f32x4 vh = *reinterpret_cast<const f32x4*>(th + rl * 68 + c4);
      __builtin_nontemporal_store(vc,
          reinterpret_cast<f32x4*>(opc + (size_t)m * 16 * HDIM));
      __builtin_nontemporal_store(vh,
          reinterpret_cast<f32x4*>(oph + (size_t)m * 16 * HDIM));
    }
    if (m < 3) LBAR();                   // reads done before next overwrite
  }
}

extern "C" void kernel_launch(void* const* d_in, const int* in_sizes, int n_in,
                              void* d_out, int out_size, void* d_ws, size_t ws_size,
                              hipStream_t stream) {
  const float* x  = (const float*)d_in[0];
  const float* C  = (const float*)d_in[1];
  const float* h  = (const float*)d_in[2];
  const float* Wx = (const float*)d_in[3];
  const float* Wh = (const float*)d_in[4];
  const float* bx = (const float*)d_in[5];
  const float* bh = (const float*)d_in[6];
  float* o = (float*)d_out;
  unsigned short* ws = (unsigned short*)d_ws;   // ~98 MiB used

  prep_all<<<dim3(24768), dim3(256), 0, stream>>>(x, h, Wx, Wh, bx, bh, ws);
  lstm_main<<<dim3(4096), dim3(512), 0, stream>>>(ws, C, o);
}